// Round 4
// baseline (101.968 us; speedup 1.0000x reference)
//
#include <hip/hip_runtime.h>
#include <math.h>

#define VOCABN 6
#define DIM 32
#define PADI 5
#define BATCH 256
#define SEQ 4096
#define KSEL 614   // int(4096 * 0.15)

// 6-way register LUT (indices are compile-time; stays in VGPRs as cndmask chain)
__device__ __forceinline__ float lut6(float s0, float s1, float s2, float s3,
                                      float s4, float s5, int tk) {
    float r = s0;
    r = (tk == 1) ? s1 : r;
    r = (tk == 2) ? s2 : r;
    r = (tk == 3) ? s3 : r;
    r = (tk == 4) ? s4 : r;
    r = (tk == 5) ? s5 : r;
    return r;
}

// One block per batch row, 1024 threads. Selector MLP is computed redundantly
// per-wave in registers (shfl reduce + broadcast): the 4 MB scores store needs
// ZERO barriers after the x load. Scatter needs only 2 barriers. The ~80 us of
// harness re-poison/restore per timed iteration is outside our control.
__global__ __launch_bounds__(1024) void fused_row_kernel(
    const int* __restrict__ x,
    const float* __restrict__ emb,
    const float* __restrict__ sel_w1, const float* __restrict__ sel_b1,
    const float* __restrict__ sel_w2, const float* __restrict__ sel_b2,
    const float* __restrict__ app_w1, const float* __restrict__ app_b1,
    const float* __restrict__ app_w2, const float* __restrict__ app_b2,
    const float* __restrict__ cls_w1, const float* __restrict__ cls_b1,
    const float* __restrict__ cls_w2, const float* __restrict__ cls_b2,
    float* __restrict__ out_pred,
    float* __restrict__ out_topidx,
    float* __restrict__ out_scores) {
    const int b = blockIdx.x;
    const int t = threadIdx.x;
    const int lane = t & 63;
    const int w = t >> 6;          // 16 waves

    __shared__ float s_emb[VOCABN * DIM];        // 192
    __shared__ float s_appw1[DIM * DIM];         // 1024
    __shared__ float s_appw2[DIM * DIM];         // 1024
    __shared__ float s_appb1[DIM], s_appb2[DIM];
    __shared__ float s_clsw1[DIM * (DIM / 2)];   // 512
    __shared__ float s_clsb1[DIM / 2], s_clsw2[DIM / 2];
    __shared__ float s_clsb2v;
    __shared__ float s_ah[VOCABN * DIM];         // 192
    __shared__ float s_a[VOCABN * DIM];          // 192
    __shared__ int s_wtot[16][VOCABN];
    __shared__ int s_sel[VOCABN], s_base[VOCABN];
    __shared__ float s_pooled[DIM], s_c[DIM / 2];

    // --- issue token load first ---
    const int4 tw = *(const int4*)(x + (size_t)b * SEQ + t * 4);

    // --- stage app/cls weights into LDS (selector stays in registers) ---
    s_appw1[t] = app_w1[t];
    s_appw2[t] = app_w2[t];
    if (t < 512) s_clsw1[t] = cls_w1[t];
    else if (t < 704) { int i = t - 512; s_emb[i] = (i >= PADI * DIM) ? 0.f : emb[i]; }
    else if (t < 736) { int i = t - 704; s_appb1[i] = app_b1[i]; }
    else if (t < 768) { int i = t - 736; s_appb2[i] = app_b2[i]; }
    else if (t < 784) { int i = t - 768; s_clsb1[i] = cls_b1[i]; }
    else if (t < 800) { int i = t - 784; s_clsw2[i] = cls_w2[i]; }
    else if (t == 800) s_clsb2v = cls_b2[0];

    // --- per-wave redundant selector MLP (no LDS, no barrier) ---
    // lane -> (v = lane/8 mod 6, hidden pair j0 = (lane&7)*2); shfl-reduce the
    // 8 partial dot products; broadcast the 6 sigmoids to every lane.
    int sv = lane >> 3; if (sv >= VOCABN) sv -= VOCABN;   // lanes 48-63 redundant
    const int j0 = (lane & 7) * 2;
    const float2 bj = *(const float2*)(sel_b1 + j0);
    const float2 wj = *(const float2*)(sel_w2 + j0);
    float h0 = bj.x, h1 = bj.y;
    if (sv != PADI) {
        const float4* e4 = (const float4*)(emb + sv * DIM);
        #pragma unroll
        for (int q = 0; q < 8; ++q) {
            const float4 e = e4[q];
            const float2 wa = *(const float2*)(sel_w1 + (q * 4 + 0) * (DIM / 2) + j0);
            const float2 wb = *(const float2*)(sel_w1 + (q * 4 + 1) * (DIM / 2) + j0);
            const float2 wc = *(const float2*)(sel_w1 + (q * 4 + 2) * (DIM / 2) + j0);
            const float2 wd = *(const float2*)(sel_w1 + (q * 4 + 3) * (DIM / 2) + j0);
            h0 += e.x * wa.x + e.y * wb.x + e.z * wc.x + e.w * wd.x;
            h1 += e.x * wa.y + e.y * wb.y + e.z * wc.y + e.w * wd.y;
        }
    }
    float part = fmaxf(h0, 0.f) * wj.x + fmaxf(h1, 0.f) * wj.y;
    part += __shfl_xor(part, 1, 64);
    part += __shfl_xor(part, 2, 64);
    part += __shfl_xor(part, 4, 64);
    const float sig = 1.f / (1.f + expf(-(part + sel_b2[0])));
    const float sc0 = __shfl(sig,  0, 64);
    const float sc1 = __shfl(sig,  8, 64);
    const float sc2 = __shfl(sig, 16, 64);
    const float sc3 = __shfl(sig, 24, 64);
    const float sc4 = __shfl(sig, 32, 64);
    const float sc5 = __shfl(sig, 40, 64);

    int tok[4];
    tok[0] = tw.x; tok[1] = tw.y; tok[2] = tw.z; tok[3] = tw.w;

    // --- bulk scores store: no barrier was needed ---
    {
        float4 f;
        f.x = lut6(sc0, sc1, sc2, sc3, sc4, sc5, tok[0]);
        f.y = lut6(sc0, sc1, sc2, sc3, sc4, sc5, tok[1]);
        f.z = lut6(sc0, sc1, sc2, sc3, sc4, sc5, tok[2]);
        f.w = lut6(sc0, sc1, sc2, sc3, sc4, sc5, tok[3]);
        *(float4*)(out_scores + (size_t)b * SEQ + t * 4) = f;
    }

    // --- histogram + intra-wave inclusive scan ---
    int cnt[VOCABN], val[VOCABN];
    #pragma unroll
    for (int v = 0; v < VOCABN; ++v) {
        int c = 0;
        #pragma unroll
        for (int i = 0; i < 4; ++i) c += (tok[i] == v) ? 1 : 0;
        cnt[v] = c; val[v] = c;
    }
    for (int off = 1; off < 64; off <<= 1) {
        #pragma unroll
        for (int v = 0; v < VOCABN; ++v) {
            int up = __shfl_up(val[v], off, 64);
            if (lane >= off) val[v] += up;
        }
    }
    if (lane == 63) {
        #pragma unroll
        for (int v = 0; v < VOCABN; ++v) s_wtot[w][v] = val[v];
    }
    __syncthreads();   // B1: wtot + weight staging visible

    // cross-wave exclusive prefix
    int excl[VOCABN];
    #pragma unroll
    for (int v = 0; v < VOCABN; ++v) {
        int pre = 0;
        for (int ww = 0; ww < w; ++ww) pre += s_wtot[ww][v];
        excl[v] = pre + val[v] - cnt[v];
    }

    // t0: rank vocab by score desc (stable, lower id first) from its own regs
    if (t == 0) {
        float scv[VOCABN] = {sc0, sc1, sc2, sc3, sc4, sc5};
        int rank[VOCABN];
        #pragma unroll
        for (int v = 0; v < VOCABN; ++v) {
            int r = 0;
            for (int u = 0; u < VOCABN; ++u) {
                if (scv[u] > scv[v]) ++r;
                else if (scv[u] == scv[v] && u < v) ++r;
            }
            rank[r] = v;
        }
        int rem = KSEL;
        for (int r = 0; r < VOCABN; ++r) {
            const int v = rank[r];
            int tot = 0;
            for (int ww = 0; ww < 16; ++ww) tot += s_wtot[ww][v];
            const int take = tot < rem ? tot : rem;
            s_base[v] = KSEL - rem;
            s_sel[v] = take;
            rem -= take;
        }
    }
    // approximator hidden layer overlaps t0's serial work
    if (t >= 128 && t < 128 + VOCABN * DIM) {
        const int i = t - 128, v = i >> 5, j = i & 31;
        float acc = s_appb1[j];
        #pragma unroll
        for (int d = 0; d < DIM; ++d) acc += s_emb[v * DIM + d] * s_appw1[d * DIM + j];
        s_ah[i] = fmaxf(acc, 0.f);
    }
    __syncthreads();   // B2: sel/base + ah visible

    // --- scatter top_idx (float; ints < 4096 exact) ---
    #pragma unroll
    for (int v = 0; v < VOCABN; ++v) {
        int p = excl[v];
        const int sel = s_sel[v];
        const int bs = s_base[v];
        #pragma unroll
        for (int i = 0; i < 4; ++i) {
            if (tok[i] == v) {
                if (p < sel) out_topidx[(size_t)b * KSEL + bs + p] = (float)(t * 4 + i);
                ++p;
            }
        }
    }

    // approximator output
    if (t >= 128 && t < 128 + VOCABN * DIM) {
        const int i = t - 128, v = i >> 5, d = i & 31;
        float acc = s_appb2[d];
        #pragma unroll
        for (int j = 0; j < DIM; ++j) acc += s_ah[v * DIM + j] * s_appw2[j * DIM + d];
        s_a[i] = acc;
    }
    __syncthreads();   // B3

    if (t < DIM) {
        float acc = 0.f;
        #pragma unroll
        for (int v = 0; v < VOCABN; ++v) acc += (float)s_sel[v] * s_a[v * DIM + t];
        s_pooled[t] = acc / (float)KSEL;
    }
    __syncthreads();   // B4
    if (t < DIM / 2) {
        float acc = s_clsb1[t];
        #pragma unroll
        for (int d = 0; d < DIM; ++d) acc += s_pooled[d] * s_clsw1[d * (DIM / 2) + t];
        s_c[t] = fmaxf(acc, 0.f);
    }
    __syncthreads();   // B5
    if (t == 0) {
        float z = s_clsb2v;
        #pragma unroll
        for (int j = 0; j < DIM / 2; ++j) z += s_c[j] * s_clsw2[j];
        out_pred[b] = 1.f / (1.f + expf(-z));
    }
}

extern "C" void kernel_launch(void* const* d_in, const int* in_sizes, int n_in,
                              void* d_out, int out_size, void* d_ws, size_t ws_size,
                              hipStream_t stream) {
    const int*   x      = (const int*)  d_in[0];
    const float* emb    = (const float*)d_in[1];
    const float* sel_w1 = (const float*)d_in[2];
    const float* sel_b1 = (const float*)d_in[3];
    const float* sel_w2 = (const float*)d_in[4];
    const float* sel_b2 = (const float*)d_in[5];
    const float* app_w1 = (const float*)d_in[6];
    const float* app_b1 = (const float*)d_in[7];
    const float* app_w2 = (const float*)d_in[8];
    const float* app_b2 = (const float*)d_in[9];
    const float* cls_w1 = (const float*)d_in[10];
    const float* cls_b1 = (const float*)d_in[11];
    const float* cls_w2 = (const float*)d_in[12];
    const float* cls_b2 = (const float*)d_in[13];

    float* out = (float*)d_out;
    float* out_pred   = out;                         // [256]
    float* out_topidx = out + BATCH;                 // [256*614] stored as float
    float* out_scores = out + BATCH + BATCH * KSEL;  // [256*4096]

    fused_row_kernel<<<BATCH, 1024, 0, stream>>>(
        x, emb, sel_w1, sel_b1, sel_w2, sel_b2,
        app_w1, app_b1, app_w2, app_b2,
        cls_w1, cls_b1, cls_w2, cls_b2,
        out_pred, out_topidx, out_scores);
}

// Round 5
// 99.416 us; speedup vs baseline: 1.0257x; 1.0257x over previous
//
#include <hip/hip_runtime.h>
#include <math.h>

#define VOCABN 6
#define DIM 32
#define PADI 5
#define BATCH 256
#define SEQ 4096
#define KSEL 614   // int(4096 * 0.15)

// 6-way register LUT (compile-time indices -> cndmask chain, no LDS)
__device__ __forceinline__ float lut6(float s0, float s1, float s2, float s3,
                                      float s4, float s5, int tk) {
    float r = s0;
    r = (tk == 1) ? s1 : r;
    r = (tk == 2) ? s2 : r;
    r = (tk == 3) ? s3 : r;
    r = (tk == 4) ? s4 : r;
    r = (tk == 5) ? s5 : r;
    return r;
}

// One block per batch row, 1024 threads, exactly ONE __syncthreads.
//   stage weights to LDS (coalesced, ~4 loads/thread)  ||  x load
//   histogram + intra-wave shfl scan -> wtot to LDS
//   B1
//   per-wave: selector MLP from LDS (regs, shfl reduce) -> scores store
//   per-wave: redundant rank/take from wtot -> scatter (no 2nd barrier)
//   wave 1 only: approximator + classifier via intra-wave shfl -> pred
// R3 post-mortem: selector weight reads must come from LDS (cooperative
// staging), not per-lane global gathers — that was the 12 us regression.
__global__ __launch_bounds__(1024) void fused_row_kernel(
    const int* __restrict__ x,
    const float* __restrict__ emb,
    const float* __restrict__ sel_w1, const float* __restrict__ sel_b1,
    const float* __restrict__ sel_w2, const float* __restrict__ sel_b2,
    const float* __restrict__ app_w1, const float* __restrict__ app_b1,
    const float* __restrict__ app_w2, const float* __restrict__ app_b2,
    const float* __restrict__ cls_w1, const float* __restrict__ cls_b1,
    const float* __restrict__ cls_w2, const float* __restrict__ cls_b2,
    float* __restrict__ out_pred,
    float* __restrict__ out_topidx,
    float* __restrict__ out_scores) {
    const int b = blockIdx.x;
    const int t = threadIdx.x;
    const int lane = t & 63;
    const int w = t >> 6;          // 16 waves

    __shared__ float s_emb[VOCABN * DIM];        // 192 (row PADI zeroed)
    __shared__ float s_selw1[DIM * (DIM / 2)];   // 512
    __shared__ float s_selb1[DIM / 2], s_selw2[DIM / 2];
    __shared__ float s_selb2, s_clsb2v;
    __shared__ float s_appw1[DIM * DIM];         // 1024
    __shared__ float s_appw2[DIM * DIM];         // 1024
    __shared__ float s_appb1[DIM], s_appb2[DIM];
    __shared__ float s_clsw1[DIM * (DIM / 2)];   // 512
    __shared__ float s_clsb1[DIM / 2], s_clsw2[DIM / 2];
    __shared__ int s_wtot[16][VOCABN];

    // --- issue token load first (latency overlaps staging) ---
    const int4 tw = *(const int4*)(x + (size_t)b * SEQ + t * 4);

    // --- cooperative coalesced weight staging, <=4 loads/thread ---
    s_appw1[t] = app_w1[t];
    s_appw2[t] = app_w2[t];
    if (t < 512) s_selw1[t] = sel_w1[t];
    else s_clsw1[t - 512] = cls_w1[t - 512];
    if (t < 192) s_emb[t] = (t >= PADI * DIM) ? 0.f : emb[t];
    else if (t < 208) { int i = t - 192; s_selb1[i] = sel_b1[i]; }
    else if (t < 224) { int i = t - 208; s_selw2[i] = sel_w2[i]; }
    else if (t < 256) { int i = t - 224; s_appb1[i] = app_b1[i]; }
    else if (t < 288) { int i = t - 256; s_appb2[i] = app_b2[i]; }
    else if (t < 304) { int i = t - 288; s_clsb1[i] = cls_b1[i]; }
    else if (t < 320) { int i = t - 304; s_clsw2[i] = cls_w2[i]; }
    else if (t == 320) s_selb2 = sel_b2[0];
    else if (t == 321) s_clsb2v = cls_b2[0];

    int tok[4];
    tok[0] = tw.x; tok[1] = tw.y; tok[2] = tw.z; tok[3] = tw.w;

    // --- histogram + intra-wave inclusive scan (shfl only, pre-barrier) ---
    int cnt[VOCABN], val[VOCABN];
    #pragma unroll
    for (int v = 0; v < VOCABN; ++v) {
        int c = 0;
        #pragma unroll
        for (int i = 0; i < 4; ++i) c += (tok[i] == v) ? 1 : 0;
        cnt[v] = c; val[v] = c;
    }
    for (int off = 1; off < 64; off <<= 1) {
        #pragma unroll
        for (int v = 0; v < VOCABN; ++v) {
            int up = __shfl_up(val[v], off, 64);
            if (lane >= off) val[v] += up;
        }
    }
    if (lane == 63) {
        #pragma unroll
        for (int v = 0; v < VOCABN; ++v) s_wtot[w][v] = val[v];
    }

    __syncthreads();   // B1 — the only barrier: staging + wtot visible

    // --- per-wave selector MLP from LDS (lane -> vocab=lane/8, 2 hidden units) ---
    int sv = lane >> 3; if (sv >= VOCABN) sv -= VOCABN;   // lanes 48-63 redundant
    const int j0 = (lane & 7) * 2;
    float h0 = s_selb1[j0], h1 = s_selb1[j0 + 1];
    #pragma unroll
    for (int d = 0; d < DIM; ++d) {
        const float e = s_emb[sv * DIM + d];
        h0 += e * s_selw1[d * (DIM / 2) + j0];
        h1 += e * s_selw1[d * (DIM / 2) + j0 + 1];
    }
    float part = fmaxf(h0, 0.f) * s_selw2[j0] + fmaxf(h1, 0.f) * s_selw2[j0 + 1];
    part += __shfl_xor(part, 1, 64);
    part += __shfl_xor(part, 2, 64);
    part += __shfl_xor(part, 4, 64);
    const float sig = 1.f / (1.f + expf(-(part + s_selb2)));
    const float sc0 = __shfl(sig,  0, 64);
    const float sc1 = __shfl(sig,  8, 64);
    const float sc2 = __shfl(sig, 16, 64);
    const float sc3 = __shfl(sig, 24, 64);
    const float sc4 = __shfl(sig, 32, 64);
    const float sc5 = __shfl(sig, 40, 64);

    // --- bulk scores store ---
    {
        float4 f;
        f.x = lut6(sc0, sc1, sc2, sc3, sc4, sc5, tok[0]);
        f.y = lut6(sc0, sc1, sc2, sc3, sc4, sc5, tok[1]);
        f.z = lut6(sc0, sc1, sc2, sc3, sc4, sc5, tok[2]);
        f.w = lut6(sc0, sc1, sc2, sc3, sc4, sc5, tok[3]);
        *(float4*)(out_scores + (size_t)b * SEQ + t * 4) = f;
    }

    // --- redundant per-lane rank/take (deterministic; same result everywhere) ---
    const float scv[VOCABN] = {sc0, sc1, sc2, sc3, sc4, sc5};
    int totv[VOCABN];
    #pragma unroll
    for (int v = 0; v < VOCABN; ++v) {
        int tot = 0;
        for (int ww = 0; ww < 16; ++ww) tot += s_wtot[ww][v];  // broadcast reads
        totv[v] = tot;
    }
    int rk[VOCABN];
    #pragma unroll
    for (int v = 0; v < VOCABN; ++v) {
        int r = 0;
        #pragma unroll
        for (int u = 0; u < VOCABN; ++u) {
            if (scv[u] > scv[v]) ++r;
            else if (scv[u] == scv[v] && u < v) ++r;
        }
        rk[v] = r;
    }
    int selv[VOCABN], basev[VOCABN];
    #pragma unroll
    for (int v = 0; v < VOCABN; ++v) {
        int before = 0;
        #pragma unroll
        for (int u = 0; u < VOCABN; ++u) before += (rk[u] < rk[v]) ? totv[u] : 0;
        const int base = before < KSEL ? before : KSEL;
        int take = KSEL - base;
        take = totv[v] < take ? totv[v] : take;
        basev[v] = base;
        selv[v] = take > 0 ? take : 0;
    }

    // --- scatter top_idx (float; ints < 4096 exact) — no 2nd barrier needed ---
    int excl[VOCABN];
    #pragma unroll
    for (int v = 0; v < VOCABN; ++v) {
        int pre = 0;
        for (int ww = 0; ww < w; ++ww) pre += s_wtot[ww][v];
        excl[v] = pre + val[v] - cnt[v];
    }
    #pragma unroll
    for (int v = 0; v < VOCABN; ++v) {
        int p = excl[v];
        #pragma unroll
        for (int i = 0; i < 4; ++i) {
            if (tok[i] == v) {
                if (p < selv[v]) out_topidx[(size_t)b * KSEL + basev[v] + p] = (float)(t * 4 + i);
                ++p;
            }
        }
    }

    // --- wave 1 alone: approximator (6 vocab serial, intra-wave shfl) + classifier ---
    if (w == 1) {
        float pooled = 0.f;                       // lane d < 32 holds pooled[d]
        #pragma unroll
        for (int v = 0; v < VOCABN; ++v) {
            float ah = 0.f;
            if (lane < DIM) {
                ah = s_appb1[lane];
                #pragma unroll
                for (int d = 0; d < DIM; ++d) ah += s_emb[v * DIM + d] * s_appw1[d * DIM + lane];
                ah = fmaxf(ah, 0.f);
            }
            float av = (lane < DIM) ? s_appb2[lane] : 0.f;
            #pragma unroll
            for (int j = 0; j < DIM; ++j) {
                const float ahj = __shfl(ah, j, 64);
                if (lane < DIM) av += ahj * s_appw2[j * DIM + lane];
            }
            pooled += (float)selv[v] * av;
        }
        pooled *= (1.f / (float)KSEL);
        float c = (lane < DIM / 2) ? s_clsb1[lane] : 0.f;
        #pragma unroll
        for (int d = 0; d < DIM; ++d) {
            const float pd = __shfl(pooled, d, 64);
            if (lane < DIM / 2) c += pd * s_clsw1[d * (DIM / 2) + lane];
        }
        float term = (lane < DIM / 2) ? fmaxf(c, 0.f) * s_clsw2[lane] : 0.f;
        term += __shfl_xor(term, 1, 64);
        term += __shfl_xor(term, 2, 64);
        term += __shfl_xor(term, 4, 64);
        term += __shfl_xor(term, 8, 64);
        if (lane == 0) out_pred[b] = 1.f / (1.f + expf(-(term + s_clsb2v)));
    }
}

extern "C" void kernel_launch(void* const* d_in, const int* in_sizes, int n_in,
                              void* d_out, int out_size, void* d_ws, size_t ws_size,
                              hipStream_t stream) {
    const int*   x      = (const int*)  d_in[0];
    const float* emb    = (const float*)d_in[1];
    const float* sel_w1 = (const float*)d_in[2];
    const float* sel_b1 = (const float*)d_in[3];
    const float* sel_w2 = (const float*)d_in[4];
    const float* sel_b2 = (const float*)d_in[5];
    const float* app_w1 = (const float*)d_in[6];
    const float* app_b1 = (const float*)d_in[7];
    const float* app_w2 = (const float*)d_in[8];
    const float* app_b2 = (const float*)d_in[9];
    const float* cls_w1 = (const float*)d_in[10];
    const float* cls_b1 = (const float*)d_in[11];
    const float* cls_w2 = (const float*)d_in[12];
    const float* cls_b2 = (const float*)d_in[13];

    float* out = (float*)d_out;
    float* out_pred   = out;                         // [256]
    float* out_topidx = out + BATCH;                 // [256*614] stored as float
    float* out_scores = out + BATCH + BATCH * KSEL;  // [256*4096]

    fused_row_kernel<<<BATCH, 1024, 0, stream>>>(
        x, emb, sel_w1, sel_b1, sel_w2, sel_b2,
        app_w1, app_b1, app_w2, app_b2,
        cls_w1, cls_b1, cls_w2, cls_b2,
        out_pred, out_topidx, out_scores);
}

// Round 6
// 89.333 us; speedup vs baseline: 1.1414x; 1.1129x over previous
//
#include <hip/hip_runtime.h>
#include <math.h>

#define VOCABN 6
#define DIM 32
#define PADI 5
#define BATCH 256
#define SEQ 4096
#define KSEL 614   // int(4096 * 0.15)

// One block per batch row, 1024 threads (16 waves), exactly TWO barriers.
// R4 post-mortem: redundant per-wave LDS work serializes on the CU's LDS
// pipe (~5.8 cyc/issue) — compute once per block, share via barrier.
//   pre-B0 : x load || coalesced weight staging; histogram + wave shfl scan
//   B0
//   P1     : wave0 = selector MLP + rank/take (writes s_score, s_selbase)
//            wave1 = cross-wave prefix -> s_wpre   (kills R2's O(w) loop)
//            waves2-4 = approximator hidden -> s_ah
//   B1
//   P2     : all waves: scores store + topidx scatter (6+6+4 ds issues/wave)
//            wave5 alone: app-out + pooled + classifier -> pred (no barrier)
__global__ __launch_bounds__(1024) void fused_row_kernel(
    const int* __restrict__ x,
    const float* __restrict__ emb,
    const float* __restrict__ sel_w1, const float* __restrict__ sel_b1,
    const float* __restrict__ sel_w2, const float* __restrict__ sel_b2,
    const float* __restrict__ app_w1, const float* __restrict__ app_b1,
    const float* __restrict__ app_w2, const float* __restrict__ app_b2,
    const float* __restrict__ cls_w1, const float* __restrict__ cls_b1,
    const float* __restrict__ cls_w2, const float* __restrict__ cls_b2,
    float* __restrict__ out_pred,
    float* __restrict__ out_topidx,
    float* __restrict__ out_scores) {
    const int b = blockIdx.x;
    const int t = threadIdx.x;
    const int lane = t & 63;
    const int w = t >> 6;          // 16 waves

    __shared__ float s_emb[VOCABN * DIM];        // 192 (row PADI zeroed)
    __shared__ float s_selw1[DIM * (DIM / 2)];   // 512
    __shared__ float s_selb1[DIM / 2], s_selw2[DIM / 2];
    __shared__ float s_selb2, s_clsb2v;
    __shared__ float s_appw1[DIM * DIM];         // 1024
    __shared__ float s_appw2[DIM * DIM];         // 1024
    __shared__ float s_appb1[DIM], s_appb2[DIM];
    __shared__ float s_clsw1[DIM * (DIM / 2)];   // 512
    __shared__ float s_clsb1[DIM / 2], s_clsw2[DIM / 2];
    __shared__ float s_ah[VOCABN * DIM];         // 192 app hidden
    __shared__ float s_score[VOCABN];
    __shared__ int s_wtot[16][VOCABN];           // per-wave inclusive totals
    __shared__ int s_wpre[16][VOCABN];           // cross-wave exclusive prefix
    __shared__ int s_selbase[VOCABN];            // sel | (base<<16)

    // --- issue token load first (latency overlaps staging) ---
    const int4 tw = *(const int4*)(x + (size_t)b * SEQ + t * 4);

    // --- cooperative coalesced weight staging, <=4 loads/thread ---
    s_appw1[t] = app_w1[t];
    s_appw2[t] = app_w2[t];
    if (t < 512) s_selw1[t] = sel_w1[t];
    else s_clsw1[t - 512] = cls_w1[t - 512];
    if (t < 192) s_emb[t] = (t >= PADI * DIM) ? 0.f : emb[t];
    else if (t < 208) { int i = t - 192; s_selb1[i] = sel_b1[i]; }
    else if (t < 224) { int i = t - 208; s_selw2[i] = sel_w2[i]; }
    else if (t < 256) { int i = t - 224; s_appb1[i] = app_b1[i]; }
    else if (t < 288) { int i = t - 256; s_appb2[i] = app_b2[i]; }
    else if (t < 304) { int i = t - 288; s_clsb1[i] = cls_b1[i]; }
    else if (t < 320) { int i = t - 304; s_clsw2[i] = cls_w2[i]; }
    else if (t == 320) s_selb2 = sel_b2[0];
    else if (t == 321) s_clsb2v = cls_b2[0];

    int tok[4];
    tok[0] = tw.x; tok[1] = tw.y; tok[2] = tw.z; tok[3] = tw.w;

    // --- histogram + intra-wave inclusive scan (shfl only) ---
    int cnt[VOCABN], val[VOCABN];
    #pragma unroll
    for (int v = 0; v < VOCABN; ++v) {
        int c = 0;
        #pragma unroll
        for (int i = 0; i < 4; ++i) c += (tok[i] == v) ? 1 : 0;
        cnt[v] = c; val[v] = c;
    }
    for (int off = 1; off < 64; off <<= 1) {
        #pragma unroll
        for (int v = 0; v < VOCABN; ++v) {
            int up = __shfl_up(val[v], off, 64);
            if (lane >= off) val[v] += up;
        }
    }
    if (lane == 63) {
        #pragma unroll
        for (int v = 0; v < VOCABN; ++v) s_wtot[w][v] = val[v];
    }

    __syncthreads();   // B0: staging + wtot visible

    if (w == 0) {
        // --- selector MLP: lane -> vocab=lane/8 (wrap), hidden pair (lane&7)*2 ---
        int sv = lane >> 3; if (sv >= VOCABN) sv -= VOCABN;
        const int j0 = (lane & 7) * 2;
        const float2 bj = *(const float2*)(s_selb1 + j0);
        const float2 wj = *(const float2*)(s_selw2 + j0);
        float h0 = bj.x, h1 = bj.y;
        #pragma unroll
        for (int d = 0; d < DIM; ++d) {
            const float e = s_emb[sv * DIM + d];
            const float2 ww = *(const float2*)(s_selw1 + d * (DIM / 2) + j0);
            h0 += e * ww.x;
            h1 += e * ww.y;
        }
        float part = fmaxf(h0, 0.f) * wj.x + fmaxf(h1, 0.f) * wj.y;
        part += __shfl_xor(part, 1, 64);
        part += __shfl_xor(part, 2, 64);
        part += __shfl_xor(part, 4, 64);
        const float sig = 1.f / (1.f + expf(-(part + s_selb2)));
        float scv[VOCABN];
        #pragma unroll
        for (int v = 0; v < VOCABN; ++v) scv[v] = __shfl(sig, v * 8, 64);
        if (lane < VOCABN) s_score[lane] = scv[lane];

        // --- totals: lane&15 -> wave ww, xor-reduce over 16-lane blocks ---
        int tv[VOCABN];
        #pragma unroll
        for (int v = 0; v < VOCABN; ++v) tv[v] = s_wtot[lane & 15][v];
        #pragma unroll
        for (int m = 1; m <= 8; m <<= 1) {
            #pragma unroll
            for (int v = 0; v < VOCABN; ++v) tv[v] += __shfl_xor(tv[v], m, 64);
        }
        // --- rank (desc score, stable low-id) + take; all lanes redundant VALU ---
        int rk[VOCABN];
        #pragma unroll
        for (int v = 0; v < VOCABN; ++v) {
            int r = 0;
            #pragma unroll
            for (int u = 0; u < VOCABN; ++u) {
                if (scv[u] > scv[v]) ++r;
                else if (scv[u] == scv[v] && u < v) ++r;
            }
            rk[v] = r;
        }
        if (lane < VOCABN) {
            const int v = lane;
            int before = 0;
            #pragma unroll
            for (int u = 0; u < VOCABN; ++u) before += (rk[u] < rk[v]) ? tv[u] : 0;
            const int base = before < KSEL ? before : KSEL;
            int take = KSEL - base;
            take = tv[v] < take ? tv[v] : take;
            take = take > 0 ? take : 0;
            s_selbase[v] = take | (base << 16);
        }
    } else if (w == 1) {
        // --- cross-wave exclusive prefix of wtot -> s_wpre ---
        int tv[VOCABN], inc[VOCABN];
        #pragma unroll
        for (int v = 0; v < VOCABN; ++v) { tv[v] = s_wtot[lane & 15][v]; inc[v] = tv[v]; }
        #pragma unroll
        for (int off = 1; off <= 8; off <<= 1) {
            #pragma unroll
            for (int v = 0; v < VOCABN; ++v) {
                int up = __shfl_up(inc[v], off, 64);
                if ((lane & 15) >= off) inc[v] += up;
            }
        }
        if (lane < 16) {
            #pragma unroll
            for (int v = 0; v < VOCABN; ++v) s_wpre[lane][v] = inc[v] - tv[v];
        }
    } else if (w >= 2 && w < 5) {
        // --- approximator hidden layer: 192 threads ---
        const int i = t - 128, v = i >> 5, j = i & 31;
        float acc = s_appb1[j];
        #pragma unroll
        for (int d = 0; d < DIM; ++d) acc += s_emb[v * DIM + d] * s_appw1[d * DIM + j];
        s_ah[i] = fmaxf(acc, 0.f);
    }

    __syncthreads();   // B1: score, selbase, wpre, ah visible

    // --- bulk scores store (6-entry LDS gather, broadcast-class) ---
    {
        float4 f;
        f.x = s_score[tok[0]]; f.y = s_score[tok[1]];
        f.z = s_score[tok[2]]; f.w = s_score[tok[3]];
        *(float4*)(out_scores + (size_t)b * SEQ + t * 4) = f;
    }

    // --- scatter top_idx (float; ints < 4096 exact) ---
    #pragma unroll
    for (int v = 0; v < VOCABN; ++v) {
        const int sb = s_selbase[v];
        const int sel = sb & 0xffff;
        const int bs = sb >> 16;
        int p = s_wpre[w][v] + val[v] - cnt[v];
        #pragma unroll
        for (int i = 0; i < 4; ++i) {
            if (tok[i] == v) {
                if (p < sel) out_topidx[(size_t)b * KSEL + bs + p] = (float)(t * 4 + i);
                ++p;
            }
        }
    }

    // --- wave 5 alone: app output + pooled + classifier (no barrier) ---
    if (w == 5) {
        const int j = lane & 31;
        const int half = lane >> 5;
        float part = 0.f;
        #pragma unroll
        for (int r = 0; r < 3; ++r) {
            const int v = 2 * r + half;
            float av = s_appb2[j];
            #pragma unroll
            for (int k = 0; k < DIM; ++k) av += s_ah[v * DIM + k] * s_appw2[k * DIM + j];
            part += (float)(s_selbase[v] & 0xffff) * av;
        }
        float pooled = (part + __shfl_xor(part, 32, 64)) * (1.f / (float)KSEL);
        // lane d holds pooled[d] for d<32 (dup in 32..63)
        float c = (lane < DIM / 2) ? s_clsb1[lane] : 0.f;
        #pragma unroll
        for (int d = 0; d < DIM; ++d) {
            const float pd = __shfl(pooled, d, 64);
            if (lane < DIM / 2) c += pd * s_clsw1[d * (DIM / 2) + lane];
        }
        float term = (lane < DIM / 2) ? fmaxf(c, 0.f) * s_clsw2[lane] : 0.f;
        term += __shfl_xor(term, 1, 64);
        term += __shfl_xor(term, 2, 64);
        term += __shfl_xor(term, 4, 64);
        term += __shfl_xor(term, 8, 64);
        if (lane == 0) out_pred[b] = 1.f / (1.f + expf(-(term + s_clsb2v)));
    }
}

extern "C" void kernel_launch(void* const* d_in, const int* in_sizes, int n_in,
                              void* d_out, int out_size, void* d_ws, size_t ws_size,
                              hipStream_t stream) {
    const int*   x      = (const int*)  d_in[0];
    const float* emb    = (const float*)d_in[1];
    const float* sel_w1 = (const float*)d_in[2];
    const float* sel_b1 = (const float*)d_in[3];
    const float* sel_w2 = (const float*)d_in[4];
    const float* sel_b2 = (const float*)d_in[5];
    const float* app_w1 = (const float*)d_in[6];
    const float* app_b1 = (const float*)d_in[7];
    const float* app_w2 = (const float*)d_in[8];
    const float* app_b2 = (const float*)d_in[9];
    const float* cls_w1 = (const float*)d_in[10];
    const float* cls_b1 = (const float*)d_in[11];
    const float* cls_w2 = (const float*)d_in[12];
    const float* cls_b2 = (const float*)d_in[13];

    float* out = (float*)d_out;
    float* out_pred   = out;                         // [256]
    float* out_topidx = out + BATCH;                 // [256*614] stored as float
    float* out_scores = out + BATCH + BATCH * KSEL;  // [256*4096]

    fused_row_kernel<<<BATCH, 1024, 0, stream>>>(
        x, emb, sel_w1, sel_b1, sel_w2, sel_b2,
        app_w1, app_b1, app_w2, app_b2,
        cls_w1, cls_b1, cls_w2, cls_b2,
        out_pred, out_topidx, out_scores);
}

// Round 7
// 88.065 us; speedup vs baseline: 1.1579x; 1.0144x over previous
//
#include <hip/hip_runtime.h>
#include <math.h>

#define VOCABN 6
#define DIM 32
#define PADI 5
#define BATCH 256
#define SEQ 4096
#define KSEL 614   // int(4096 * 0.15)

// bits of 64-bit mask set at lanes strictly below mine (v_mbcnt_lo + v_mbcnt_hi)
__device__ __forceinline__ int mbcnt64(unsigned long long m) {
    return __builtin_amdgcn_mbcnt_hi((unsigned)(m >> 32),
           __builtin_amdgcn_mbcnt_lo((unsigned)m, 0u));
}

// 6-way register LUT (compile-time indices -> cndmask chain, no LDS)
__device__ __forceinline__ float lut6(float s0, float s1, float s2, float s3,
                                      float s4, float s5, int tk) {
    float r = s0;
    r = (tk == 1) ? s1 : r;
    r = (tk == 2) ? s2 : r;
    r = (tk == 3) ? s3 : r;
    r = (tk == 4) ? s4 : r;
    r = (tk == 5) ? s5 : r;
    return r;
}

// One block per batch row, 1024 threads (16 waves), two barriers.
// R6: the intra-wave histogram scan is ballot+mbcnt (VALU/SALU only) instead
// of __shfl_up (= ds_bpermute on the ONE LDS pipe, serialized across 16
// waves: ~576 issues ~1.4 us in R5). Shared scalars are packed to 32 B rows
// and read as int4/float4 (12 broadcast LDS reads/wave -> 4).
__global__ __launch_bounds__(1024) void fused_row_kernel(
    const int* __restrict__ x,
    const float* __restrict__ emb,
    const float* __restrict__ sel_w1, const float* __restrict__ sel_b1,
    const float* __restrict__ sel_w2, const float* __restrict__ sel_b2,
    const float* __restrict__ app_w1, const float* __restrict__ app_b1,
    const float* __restrict__ app_w2, const float* __restrict__ app_b2,
    const float* __restrict__ cls_w1, const float* __restrict__ cls_b1,
    const float* __restrict__ cls_w2, const float* __restrict__ cls_b2,
    float* __restrict__ out_pred,
    float* __restrict__ out_topidx,
    float* __restrict__ out_scores) {
    const int b = blockIdx.x;
    const int t = threadIdx.x;
    const int lane = t & 63;
    const int w = t >> 6;          // 16 waves

    __shared__ float s_emb[VOCABN * DIM];        // 192 (row PADI zeroed)
    __shared__ float s_selw1[DIM * (DIM / 2)];   // 512
    __shared__ float s_selb1[DIM / 2], s_selw2[DIM / 2];
    __shared__ float s_selb2, s_clsb2v;
    __shared__ float s_appw1[DIM * DIM];         // 1024
    __shared__ float s_appw2[DIM * DIM];         // 1024
    __shared__ float s_appb1[DIM], s_appb2[DIM];
    __shared__ float s_clsw1[DIM * (DIM / 2)];   // 512
    __shared__ float s_clsb1[DIM / 2], s_clsw2[DIM / 2];
    __shared__ float s_ah[VOCABN * DIM];         // 192 app hidden
    __shared__ __align__(16) float s_score[8];
    __shared__ __align__(16) int s_wtot[16][8];  // per-wave totals (padded row)
    __shared__ __align__(16) int s_wpre[16][8];  // cross-wave exclusive prefix
    __shared__ __align__(16) int s_selbase[8];   // take | (base<<16)

    // --- issue token load first (latency overlaps staging) ---
    const int4 tw = *(const int4*)(x + (size_t)b * SEQ + t * 4);

    // --- cooperative coalesced weight staging, <=4 loads/thread ---
    s_appw1[t] = app_w1[t];
    s_appw2[t] = app_w2[t];
    if (t < 512) s_selw1[t] = sel_w1[t];
    else s_clsw1[t - 512] = cls_w1[t - 512];
    if (t < 192) s_emb[t] = (t >= PADI * DIM) ? 0.f : emb[t];
    else if (t < 208) { int i = t - 192; s_selb1[i] = sel_b1[i]; }
    else if (t < 224) { int i = t - 208; s_selw2[i] = sel_w2[i]; }
    else if (t < 256) { int i = t - 224; s_appb1[i] = app_b1[i]; }
    else if (t < 288) { int i = t - 256; s_appb2[i] = app_b2[i]; }
    else if (t < 304) { int i = t - 288; s_clsb1[i] = cls_b1[i]; }
    else if (t < 320) { int i = t - 304; s_clsw2[i] = cls_w2[i]; }
    else if (t == 320) s_selb2 = sel_b2[0];
    else if (t == 321) s_clsb2v = cls_b2[0];

    int tok[4];
    tok[0] = tw.x; tok[1] = tw.y; tok[2] = tw.z; tok[3] = tw.w;

    // --- histogram via ballot: 24 wave-uniform 64-bit masks in SGPR pairs ---
    unsigned long long msk[VOCABN][4];
    #pragma unroll
    for (int v = 0; v < VOCABN; ++v) {
        #pragma unroll
        for (int i = 0; i < 4; ++i) msk[v][i] = __ballot(tok[i] == v);
    }
    // per-wave totals: scalar popcounts, one lane writes the padded row (2 issues)
    if (lane == 0) {
        int c[VOCABN];
        #pragma unroll
        for (int v = 0; v < VOCABN; ++v)
            c[v] = __popcll(msk[v][0]) + __popcll(msk[v][1]) +
                   __popcll(msk[v][2]) + __popcll(msk[v][3]);
        *(int4*)&s_wtot[w][0] = make_int4(c[0], c[1], c[2], c[3]);
        *(int2*)&s_wtot[w][4] = make_int2(c[4], c[5]);
    }

    __syncthreads();   // B0: staging + wtot visible

    if (w == 0) {
        // --- selector MLP: lane -> vocab=lane/8 (wrap), hidden pair (lane&7)*2 ---
        int sv = lane >> 3; if (sv >= VOCABN) sv -= VOCABN;
        const int j0 = (lane & 7) * 2;
        const float2 bj = *(const float2*)(s_selb1 + j0);
        const float2 wj = *(const float2*)(s_selw2 + j0);
        float h0 = bj.x, h1 = bj.y;
        #pragma unroll
        for (int d = 0; d < DIM; ++d) {
            const float e = s_emb[sv * DIM + d];
            const float2 ww = *(const float2*)(s_selw1 + d * (DIM / 2) + j0);
            h0 += e * ww.x;
            h1 += e * ww.y;
        }
        float part = fmaxf(h0, 0.f) * wj.x + fmaxf(h1, 0.f) * wj.y;
        part += __shfl_xor(part, 1, 64);
        part += __shfl_xor(part, 2, 64);
        part += __shfl_xor(part, 4, 64);
        const float sig = 1.f / (1.f + expf(-(part + s_selb2)));
        float scv[VOCABN];
        #pragma unroll
        for (int v = 0; v < VOCABN; ++v) scv[v] = __shfl(sig, v * 8, 64);
        if (lane < VOCABN) s_score[lane] = scv[lane];

        // totals: lane&15 -> wave row, xor-reduce across the 16-lane groups
        int tv[VOCABN];
        #pragma unroll
        for (int v = 0; v < VOCABN; ++v) tv[v] = s_wtot[lane & 15][v];
        #pragma unroll
        for (int m = 1; m <= 8; m <<= 1) {
            #pragma unroll
            for (int v = 0; v < VOCABN; ++v) tv[v] += __shfl_xor(tv[v], m, 64);
        }
        // rank (desc score, stable low-id) + take
        int rk[VOCABN];
        #pragma unroll
        for (int v = 0; v < VOCABN; ++v) {
            int r = 0;
            #pragma unroll
            for (int u = 0; u < VOCABN; ++u) {
                if (scv[u] > scv[v]) ++r;
                else if (scv[u] == scv[v] && u < v) ++r;
            }
            rk[v] = r;
        }
        if (lane < VOCABN) {
            const int v = lane;
            int before = 0;
            #pragma unroll
            for (int u = 0; u < VOCABN; ++u) before += (rk[u] < rk[v]) ? tv[u] : 0;
            const int base = before < KSEL ? before : KSEL;
            int take = KSEL - base;
            take = tv[v] < take ? tv[v] : take;
            take = take > 0 ? take : 0;
            s_selbase[v] = take | (base << 16);
        }
    } else if (w == 1) {
        // cross-wave exclusive prefix of wtot -> s_wpre (one wave, 24 bpermutes)
        int tv[VOCABN], inc[VOCABN];
        #pragma unroll
        for (int v = 0; v < VOCABN; ++v) { tv[v] = s_wtot[lane & 15][v]; inc[v] = tv[v]; }
        #pragma unroll
        for (int off = 1; off <= 8; off <<= 1) {
            #pragma unroll
            for (int v = 0; v < VOCABN; ++v) {
                int up = __shfl_up(inc[v], off, 64);
                if ((lane & 15) >= off) inc[v] += up;
            }
        }
        if (lane < 16) {
            *(int4*)&s_wpre[lane][0] = make_int4(inc[0] - tv[0], inc[1] - tv[1],
                                                 inc[2] - tv[2], inc[3] - tv[3]);
            *(int2*)&s_wpre[lane][4] = make_int2(inc[4] - tv[4], inc[5] - tv[5]);
        }
    } else if (w >= 2 && w < 5) {
        // approximator hidden layer: 192 threads
        const int i = t - 128, v = i >> 5, j = i & 31;
        float acc = s_appb1[j];
        #pragma unroll
        for (int d = 0; d < DIM; ++d) acc += s_emb[v * DIM + d] * s_appw1[d * DIM + j];
        s_ah[i] = fmaxf(acc, 0.f);
    }

    __syncthreads();   // B1: score, selbase, wpre, ah visible

    // --- scores store: 2 vector LDS reads -> register LUT -> float4 store ---
    {
        const float4 s03 = *(const float4*)&s_score[0];
        const float2 s45 = *(const float2*)&s_score[4];
        float4 f;
        f.x = lut6(s03.x, s03.y, s03.z, s03.w, s45.x, s45.y, tok[0]);
        f.y = lut6(s03.x, s03.y, s03.z, s03.w, s45.x, s45.y, tok[1]);
        f.z = lut6(s03.x, s03.y, s03.z, s03.w, s45.x, s45.y, tok[2]);
        f.w = lut6(s03.x, s03.y, s03.z, s03.w, s45.x, s45.y, tok[3]);
        *(float4*)(out_scores + (size_t)b * SEQ + t * 4) = f;
    }

    // --- scatter top_idx: wave-uniform metadata via 4 vector LDS reads ---
    {
        const int4 wp03 = *(const int4*)&s_wpre[w][0];
        const int2 wp45 = *(const int2*)&s_wpre[w][4];
        const int4 sb03 = *(const int4*)&s_selbase[0];
        const int2 sb45 = *(const int2*)&s_selbase[4];
        const int wp[VOCABN] = {wp03.x, wp03.y, wp03.z, wp03.w, wp45.x, wp45.y};
        const int sb[VOCABN] = {sb03.x, sb03.y, sb03.z, sb03.w, sb45.x, sb45.y};
        #pragma unroll
        for (int v = 0; v < VOCABN; ++v) {
            const int sel = sb[v] & 0xffff;
            const int bs = sb[v] >> 16;
            // stable prefix among earlier lanes of this wave (VALU mbcnt)
            int p = wp[v] + mbcnt64(msk[v][0]) + mbcnt64(msk[v][1]) +
                    mbcnt64(msk[v][2]) + mbcnt64(msk[v][3]);
            #pragma unroll
            for (int i = 0; i < 4; ++i) {
                if (tok[i] == v) {
                    if (p < sel) out_topidx[(size_t)b * KSEL + bs + p] = (float)(t * 4 + i);
                    ++p;
                }
            }
        }
    }

    // --- wave 5 alone: app output + pooled + classifier (no barrier) ---
    if (w == 5) {
        const int4 sb03 = *(const int4*)&s_selbase[0];
        const int2 sb45 = *(const int2*)&s_selbase[4];
        const int sel6[VOCABN] = {sb03.x & 0xffff, sb03.y & 0xffff, sb03.z & 0xffff,
                                  sb03.w & 0xffff, sb45.x & 0xffff, sb45.y & 0xffff};
        const int j = lane & 31;
        const int half = lane >> 5;
        float part = 0.f;
        #pragma unroll
        for (int r = 0; r < 3; ++r) {
            const int v = 2 * r + half;
            float av = s_appb2[j];
            #pragma unroll
            for (int k = 0; k < DIM; ++k) av += s_ah[v * DIM + k] * s_appw2[k * DIM + j];
            part += (float)sel6[v] * av;
        }
        float pooled = (part + __shfl_xor(part, 32, 64)) * (1.f / (float)KSEL);
        float c = (lane < DIM / 2) ? s_clsb1[lane] : 0.f;
        #pragma unroll
        for (int d = 0; d < DIM; ++d) {
            const float pd = __shfl(pooled, d, 64);
            if (lane < DIM / 2) c += pd * s_clsw1[d * (DIM / 2) + lane];
        }
        float term = (lane < DIM / 2) ? fmaxf(c, 0.f) * s_clsw2[lane] : 0.f;
        term += __shfl_xor(term, 1, 64);
        term += __shfl_xor(term, 2, 64);
        term += __shfl_xor(term, 4, 64);
        term += __shfl_xor(term, 8, 64);
        if (lane == 0) out_pred[b] = 1.f / (1.f + expf(-(term + s_clsb2v)));
    }
}

extern "C" void kernel_launch(void* const* d_in, const int* in_sizes, int n_in,
                              void* d_out, int out_size, void* d_ws, size_t ws_size,
                              hipStream_t stream) {
    const int*   x      = (const int*)  d_in[0];
    const float* emb    = (const float*)d_in[1];
    const float* sel_w1 = (const float*)d_in[2];
    const float* sel_b1 = (const float*)d_in[3];
    const float* sel_w2 = (const float*)d_in[4];
    const float* sel_b2 = (const float*)d_in[5];
    const float* app_w1 = (const float*)d_in[6];
    const float* app_b1 = (const float*)d_in[7];
    const float* app_w2 = (const float*)d_in[8];
    const float* app_b2 = (const float*)d_in[9];
    const float* cls_w1 = (const float*)d_in[10];
    const float* cls_b1 = (const float*)d_in[11];
    const float* cls_w2 = (const float*)d_in[12];
    const float* cls_b2 = (const float*)d_in[13];

    float* out = (float*)d_out;
    float* out_pred   = out;                         // [256]
    float* out_topidx = out + BATCH;                 // [256*614] stored as float
    float* out_scores = out + BATCH + BATCH * KSEL;  // [256*4096]

    fused_row_kernel<<<BATCH, 1024, 0, stream>>>(
        x, emb, sel_w1, sel_b1, sel_w2, sel_b2,
        app_w1, app_b1, app_w2, app_b2,
        cls_w1, cls_b1, cls_w2, cls_b2,
        out_pred, out_topidx, out_scores);
}